// Round 5
// baseline (390.477 us; speedup 1.0000x reference)
//
#include <hip/hip_runtime.h>
#include <stdint.h>

namespace {
constexpr int kNS = 10;
// workspace float offsets
constexpr int OFF_S    = 0;        // S[j][d][h]: 128*64*32 = 262144
constexpr int OFF_U    = 262144;   // u[s][d]:    4096*64   = 262144
constexpr int OFF_SNRM = 524288;   // 80 floats: step k, cell c at [k*8+c] (8-way sharded partials)
constexpr int OFF_LOSS = 524368;   // [0]=step_loss, [1]=sum|emb-xt|
constexpr int OFF_CTR  = 524370;   // uint32[96]: step arrivals [k*8+c]; u-publish [80+c]; done [88]
}

struct KeyArr { uint32_t k0[kNS]; uint32_t k1[kNS]; };

// ---------------- threefry2x32-20 (matches jax/_src/prng.py) ----------------
__host__ __device__ inline void tf2x32(uint32_t k0, uint32_t k1, uint32_t x0, uint32_t x1,
                                       uint32_t& o0, uint32_t& o1) {
  const uint32_t k2 = k0 ^ k1 ^ 0x1BD11BDAu;
#define TF_R(r) { x0 += x1; x1 = (x1 << (r)) | (x1 >> (32 - (r))); x1 ^= x0; }
  x0 += k0; x1 += k1;
  TF_R(13) TF_R(15) TF_R(26) TF_R(6)
  x0 += k1; x1 += k2 + 1u;
  TF_R(17) TF_R(29) TF_R(16) TF_R(24)
  x0 += k2; x1 += k0 + 2u;
  TF_R(13) TF_R(15) TF_R(26) TF_R(6)
  x0 += k0; x1 += k1 + 3u;
  TF_R(17) TF_R(29) TF_R(16) TF_R(24)
  x0 += k1; x1 += k2 + 4u;
  TF_R(13) TF_R(15) TF_R(26) TF_R(6)
  x0 += k2; x1 += k0 + 5u;
#undef TF_R
  o0 = x0; o1 = x1;
}

// partitionable threefry: bits[idx] = y0 ^ y1 of cipher(key, 0, idx)  [verified R1]
__device__ inline uint32_t rand_bits(uint32_t key0, uint32_t key1, uint32_t idx) {
  uint32_t y0, y1;
  tf2x32(key0, key1, 0u, idx, y0, y1);
  return y0 ^ y1;
}

// ------------- XLA ErfInv (f32, Giles poly) + jax.random.normal -------------
__device__ inline float erfinv_xla(float x) {
  float w = -log1pf(-x * x);
  float p;
  if (w < 5.0f) {
    w = w - 2.5f;
    p = 2.81022636e-08f;
    p = fmaf(p, w, 3.43273939e-07f);
    p = fmaf(p, w, -3.5233877e-06f);
    p = fmaf(p, w, -4.39150654e-06f);
    p = fmaf(p, w, 0.00021858087f);
    p = fmaf(p, w, -0.00125372503f);
    p = fmaf(p, w, -0.00417768164f);
    p = fmaf(p, w, 0.246640727f);
    p = fmaf(p, w, 1.50140941f);
  } else {
    w = sqrtf(w) - 3.0f;
    p = -0.000200214257f;
    p = fmaf(p, w, 0.000100950558f);
    p = fmaf(p, w, 0.00134934322f);
    p = fmaf(p, w, -0.00367342844f);
    p = fmaf(p, w, 0.00573950773f);
    p = fmaf(p, w, -0.0076224613f);
    p = fmaf(p, w, 0.00943887047f);
    p = fmaf(p, w, 1.00167406f);
    p = fmaf(p, w, 2.83297682f);
  }
  return p * x;
}

__device__ inline float bits_to_normal(uint32_t bits) {
  const float lo = -0.99999994039535522f;  // nextafter(-1,0) in f32
  float f = __uint_as_float((bits >> 9) | 0x3f800000u) - 1.0f;
  float u = fmaxf(lo, f * 2.0f + lo);
  return 1.41421356237309515f * erfinv_xla(u);
}

// ---------------------------------------------------------------------------
// k_pre: S[j] = sum_{t>j} W1 row-block t. One block per j, coalesced float4.
__global__ __launch_bounds__(256) void k_pre(const float* __restrict__ W1,
                                             float* __restrict__ ws) {
  const int j = blockIdx.x;      // 128 blocks
  const int tid = threadIdx.x;
  float4 a0 = {0.f, 0.f, 0.f, 0.f}, a1 = {0.f, 0.f, 0.f, 0.f};
  for (int t = j + 1; t < 128; ++t) {
    const float4* p = (const float4*)(W1 + t * 2048);
    const float4 x0 = p[tid], x1 = p[tid + 256];
    a0.x += x0.x; a0.y += x0.y; a0.z += x0.z; a0.w += x0.w;
    a1.x += x1.x; a1.y += x1.y; a1.z += x1.z; a1.w += x1.w;
  }
  float4* Sj = (float4*)(ws + OFF_S + j * 2048);
  Sj[tid] = a0; Sj[tid + 256] = a1;
  if (j == 127) {  // zero-iteration block zeroes ALL sync state (178 words)
    if (tid < 178) ws[OFF_SNRM + tid] = 0.0f;  // snrm[80]+loss[2]+ctr[96]
  }
}

// ---------------------------------------------------------------------------
// k_main: cooperative (co-residency only — no grid.sync). 256 blocks x 256.
// Block bk owns 16 samples sharing t = bk>>1: s = t + 128*m, m in
// [(bk&1)*16, +16). Per-step inter-block sync = R3's proven primitive
// (global atomicAdd partial + release fetch_add + acquire spin), but sharded
// over 8 cells (cell = bk&7, 32 arrivals each) to cut RMW serialization.
__global__ void __launch_bounds__(256, 1) k_main(
    const float* __restrict__ emb, const float* __restrict__ W1,
    const float* __restrict__ b1, const float* __restrict__ W2,
    const float* __restrict__ b2, float* __restrict__ out,
    float* __restrict__ ws, KeyArr keys) {
  __shared__ float W1_l[64][32];    // rows t*64 .. t*64+63 of W1
  __shared__ float W2_l[32][64];
  __shared__ float base_l[16][32];
  __shared__ float u_l[16][64];
  __shared__ float score_l[16][64];
  __shared__ float h_l[16][32];
  __shared__ float b2_l[64];
  __shared__ float tW1_l[32];       // W1 last row (time feature)
  __shared__ float wsum[4];
  __shared__ float snorm_sh;
  __shared__ float loss_sh;

  const int tid  = threadIdx.x;
  const int bk   = blockIdx.x;
  const int gtid = bk * 256 + tid;
  const int t    = bk >> 1;
  const int m0   = (bk & 1) * 16;
  const int cell = bk & 7;

  float*     S      = ws + OFF_S;
  float*     u_g    = ws + OFF_U;
  float*     snrm_g = ws + OFF_SNRM;
  float*     loss_g = ws + OFF_LOSS;
  uint32_t*  ctr    = (uint32_t*)(ws + OFF_CTR);

  // ---- Phase A: persistent LDS loads ----
#pragma unroll
  for (int r = 0; r < 8; ++r) {
    const int off = r * 256 + tid;
    ((float*)W1_l)[off] = W1[t * 2048 + off];
    ((float*)W2_l)[off] = W2[off];
  }
#pragma unroll
  for (int r = 0; r < 4; ++r)
    ((float*)u_l)[r * 256 + tid] = 0.0f;
  if (tid < 64) b2_l[tid] = b2[tid];
  if (tid < 32) tW1_l[tid] = W1[262144 + tid];     // W1[8192*32 + h]
  if (tid == 0) loss_sh = 0.0f;

  // ---- Phase B: base_l[sl][h] = b1[h] + sum_d emb[b][j][d] * S[j][d][h] ----
#pragma unroll
  for (int r = 0; r < 2; ++r) {
    const int idx = r * 256 + tid;                 // 512 tasks: (sl, h)
    const int sl = idx >> 5, h = idx & 31;
    const int s = t + 128 * (m0 + sl);
    const int j = (s >> 5), b = (s & 31);
    const float* e  = emb + (b * 128 + j) * 64;
    const float* Sr = S + j * 2048 + h;
    float acc = b1[h];
#pragma unroll
    for (int d = 0; d < 64; ++d)
      acc = fmaf(e[d], Sr[d * 32], acc);
    base_l[sl][h] = acc;
  }
  __syncthreads();

  // ---- main loop: 10 SDE steps, sharded scalar sync ----
  for (int k = 0; k < kNS; ++k) {
    const float tval = (float)k * 0.1f;
    // layer 1: pre-activation + relu  (thread = (sl, h); W1_l broadcast)
#pragma unroll
    for (int r = 0; r < 2; ++r) {
      const int idx = r * 256 + tid;
      const int sl = idx >> 5, h = idx & 31;
      float pre = fmaf(tval, tW1_l[h], base_l[sl][h]);
#pragma unroll
      for (int d = 0; d < 64; ++d)
        pre = fmaf(u_l[sl][d], W1_l[d][h], pre);
      h_l[sl][h] = fmaxf(pre, 0.0f);
    }
    __syncthreads();
    // layer 2: score + snorm partial  (thread = (sl, c); c consecutive)
    float sq = 0.0f;
#pragma unroll
    for (int r = 0; r < 4; ++r) {
      const int idx = r * 256 + tid;
      const int sl = idx >> 6, c = idx & 63;
      float v = b2_l[c];
#pragma unroll
      for (int hh = 0; hh < 32; ++hh)
        v = fmaf(h_l[sl][hh], W2_l[hh][c], v);
      score_l[sl][c] = v;
      sq = fmaf(v, v, sq);
    }
#pragma unroll
    for (int o = 32; o > 0; o >>= 1) sq += __shfl_down(sq, o);
    if ((tid & 63) == 0) wsum[tid >> 6] = sq;
    __syncthreads();
    // arrive: partial into my cell + release-increment my cell's counter
    if (tid == 0) {
      atomicAdd(&snrm_g[k * 8 + cell], wsum[0] + wsum[1] + wsum[2] + wsum[3]);
      __hip_atomic_fetch_add(&ctr[k * 8 + cell], 1u,
                             __ATOMIC_RELEASE, __HIP_MEMORY_SCOPE_AGENT);
    }
    // overlap: threefry noise (snorm-independent) while other blocks arrive
    float nn[4];
    const int d = tid & 63;
#pragma unroll
    for (int r = 0; r < 4; ++r) {
      const int sl = (tid >> 6) * 4 + r;
      const int s = t + 128 * (m0 + sl);
      nn[r] = bits_to_normal(rand_bits(keys.k0[k], keys.k1[k],
                                       (uint32_t)(s * 64 + d))) * 0.31622776601683794f;
    }
    if (tid == 0) {
      for (int c = 0; c < 8; ++c)
        while (__hip_atomic_load(&ctr[k * 8 + c], __ATOMIC_ACQUIRE,
                                 __HIP_MEMORY_SCOPE_AGENT) < 32u)
          __builtin_amdgcn_s_sleep(2);
      float tot = 0.0f;
      for (int c = 0; c < 8; ++c)
        tot += __hip_atomic_load(&snrm_g[k * 8 + c], __ATOMIC_RELAXED,
                                 __HIP_MEMORY_SCOPE_AGENT);
      snorm_sh = sqrtf(tot);
    }
    __syncthreads();
    const float snorm = snorm_sh;
    // update u (d-major: consecutive lanes -> conflict-free) + diagonal loss
#pragma unroll
    for (int r = 0; r < 4; ++r) {
      const int sl = (tid >> 6) * 4 + r;           // wave-uniform
      const int s = t + 128 * (m0 + sl);
      const float dx = score_l[sl][d] * 0.05f + snorm * nn[r];
      const float un = u_l[sl][d] + dx;
      u_l[sl][d] = un;
      if ((s & 127) == (s >> 5)) {                 // diagonal sample
        float lq = un * un;
#pragma unroll
        for (int o = 32; o > 0; o >>= 1) lq += __shfl_down(lq, o);
        if ((tid & 63) == 0) atomicAdd(&loss_sh, lq * (1.0f / 64.0f));
      }
    }
    __syncthreads();
  }

  // ---- publish u (agent-scope atomic stores) + sharded barrier ----
  {
    const int d = tid & 63;
#pragma unroll
    for (int r = 0; r < 4; ++r) {
      const int sl = (tid >> 6) * 4 + r;
      const int s = t + 128 * (m0 + sl);
      __hip_atomic_store(&u_g[s * 64 + d], u_l[sl][d],
                         __ATOMIC_RELAXED, __HIP_MEMORY_SCOPE_AGENT);
    }
  }
  __syncthreads();
  if (tid == 0) {
    atomicAdd(loss_g + 0, loss_sh);
    __hip_atomic_fetch_add(&ctr[80 + cell], 1u,
                           __ATOMIC_RELEASE, __HIP_MEMORY_SCOPE_AGENT);
    for (int c = 0; c < 8; ++c)
      while (__hip_atomic_load(&ctr[80 + c], __ATOMIC_ACQUIRE,
                               __HIP_MEMORY_SCOPE_AGENT) < 32u)
        __builtin_amdgcn_s_sleep(2);
  }
  __syncthreads();

  // ---- final: assemble xt output (verified R1 index map) + |emb-xt| ----
  float lab = 0.0f;
#pragma unroll
  for (int r = 0; r < 4; ++r) {
    const int g = r * 65536 + gtid;                // covers 262144
    const int dd = g & 63, bi = g >> 6, i = bi & 127, b = bi >> 7;
    const int mm = i * 32 + b, bp = mm >> 7, tt = mm & 127;
    const int s2 = i * 32 + bp;
    float v = 0.0f;
    if (i < tt) v = emb[(bp * 128 + i) * 64 + dd];
    if ((s2 & 127) == tt)
      v += __hip_atomic_load(&u_g[s2 * 64 + dd], __ATOMIC_RELAXED, __HIP_MEMORY_SCOPE_AGENT);
    out[g] = v;
    lab += fabsf(emb[g] - v);
  }
#pragma unroll
  for (int o = 32; o > 0; o >>= 1) lab += __shfl_down(lab, o);
  if ((tid & 63) == 0) wsum[tid >> 6] = lab;
  __syncthreads();
  if (tid == 0) {
    atomicAdd(loss_g + 1, wsum[0] + wsum[1] + wsum[2] + wsum[3]);
    const uint32_t old = __hip_atomic_fetch_add(&ctr[88], 1u,
                         __ATOMIC_ACQ_REL, __HIP_MEMORY_SCOPE_AGENT);
    if (old == 255u) {  // last block: all loss adds visible
      out[262144] = __hip_atomic_load(loss_g + 0, __ATOMIC_RELAXED, __HIP_MEMORY_SCOPE_AGENT);
      out[262145] = __hip_atomic_load(loss_g + 1, __ATOMIC_RELAXED, __HIP_MEMORY_SCOPE_AGENT)
                    * (1.0f / 262144.0f);
    }
  }
}

// ---------------------------------------------------------------------------
static void compute_step_keys(KeyArr& ka) {
  for (int i = 0; i < kNS; ++i) {
    uint32_t y0, y1;
    tf2x32(0u, 42u, 0u, (uint32_t)i, y0, y1);
    ka.k0[i] = y0; ka.k1[i] = y1;
  }
}

extern "C" void kernel_launch(void* const* d_in, const int* in_sizes, int n_in,
                              void* d_out, int out_size, void* d_ws, size_t ws_size,
                              hipStream_t stream) {
  (void)in_sizes; (void)n_in; (void)out_size; (void)ws_size;
  const float* emb = (const float*)d_in[0];
  const float* W1  = (const float*)d_in[1];
  const float* b1  = (const float*)d_in[2];
  const float* W2  = (const float*)d_in[3];
  const float* b2  = (const float*)d_in[4];
  float* out = (float*)d_out;
  float* ws  = (float*)d_ws;

  KeyArr ka;
  compute_step_keys(ka);

  k_pre<<<128, 256, 0, stream>>>(W1, ws);

  void* args[] = {(void*)&emb, (void*)&W1, (void*)&b1, (void*)&W2, (void*)&b2,
                  (void*)&out, (void*)&ws, (void*)&ka};
  hipLaunchCooperativeKernel((const void*)k_main, dim3(256), dim3(256),
                             args, 0, stream);
}

// Round 6
// 222.511 us; speedup vs baseline: 1.7549x; 1.7549x over previous
//
#include <hip/hip_runtime.h>
#include <stdint.h>

namespace {
constexpr int kNS = 10;
// workspace float offsets
constexpr int OFF_S    = 0;        // S[j][d][h]: 128*64*32 = 262144
constexpr int OFF_U    = 262144;   // u[s][d]:    4096*64   = 262144
// sync slots: slot(k,c) = OFF_SYNC + (k*8+c)*32 floats (128 B apart -> no false sharing)
//   slot[0] = float partial (atomicAdd), slot[1] = uint32 arrive-ctr (fetch_add)
//   k = 0..9: step syncs; k = 10: u-publish barrier (ctr only)
constexpr int OFF_SYNC = 524288;   // 11*8*32 = 2816 floats
constexpr int OFF_LOSS = 527104;   // [0]=step_loss, [1]=sum|emb-xt|, [2](u32)=done ctr
constexpr int ZERO_CNT = 2848;     // floats to zero from OFF_SYNC
}

struct KeyArr { uint32_t k0[kNS]; uint32_t k1[kNS]; };

// ---------------- threefry2x32-20 (matches jax/_src/prng.py) ----------------
__host__ __device__ inline void tf2x32(uint32_t k0, uint32_t k1, uint32_t x0, uint32_t x1,
                                       uint32_t& o0, uint32_t& o1) {
  const uint32_t k2 = k0 ^ k1 ^ 0x1BD11BDAu;
#define TF_R(r) { x0 += x1; x1 = (x1 << (r)) | (x1 >> (32 - (r))); x1 ^= x0; }
  x0 += k0; x1 += k1;
  TF_R(13) TF_R(15) TF_R(26) TF_R(6)
  x0 += k1; x1 += k2 + 1u;
  TF_R(17) TF_R(29) TF_R(16) TF_R(24)
  x0 += k2; x1 += k0 + 2u;
  TF_R(13) TF_R(15) TF_R(26) TF_R(6)
  x0 += k0; x1 += k1 + 3u;
  TF_R(17) TF_R(29) TF_R(16) TF_R(24)
  x0 += k1; x1 += k2 + 4u;
  TF_R(13) TF_R(15) TF_R(26) TF_R(6)
  x0 += k2; x1 += k0 + 5u;
#undef TF_R
  o0 = x0; o1 = x1;
}

// partitionable threefry: bits[idx] = y0 ^ y1 of cipher(key, 0, idx)  [verified R1]
__device__ inline uint32_t rand_bits(uint32_t key0, uint32_t key1, uint32_t idx) {
  uint32_t y0, y1;
  tf2x32(key0, key1, 0u, idx, y0, y1);
  return y0 ^ y1;
}

// ------------- XLA ErfInv (f32, Giles poly) + jax.random.normal -------------
__device__ inline float erfinv_xla(float x) {
  float w = -log1pf(-x * x);
  float p;
  if (w < 5.0f) {
    w = w - 2.5f;
    p = 2.81022636e-08f;
    p = fmaf(p, w, 3.43273939e-07f);
    p = fmaf(p, w, -3.5233877e-06f);
    p = fmaf(p, w, -4.39150654e-06f);
    p = fmaf(p, w, 0.00021858087f);
    p = fmaf(p, w, -0.00125372503f);
    p = fmaf(p, w, -0.00417768164f);
    p = fmaf(p, w, 0.246640727f);
    p = fmaf(p, w, 1.50140941f);
  } else {
    w = sqrtf(w) - 3.0f;
    p = -0.000200214257f;
    p = fmaf(p, w, 0.000100950558f);
    p = fmaf(p, w, 0.00134934322f);
    p = fmaf(p, w, -0.00367342844f);
    p = fmaf(p, w, 0.00573950773f);
    p = fmaf(p, w, -0.0076224613f);
    p = fmaf(p, w, 0.00943887047f);
    p = fmaf(p, w, 1.00167406f);
    p = fmaf(p, w, 2.83297682f);
  }
  return p * x;
}

__device__ inline float bits_to_normal(uint32_t bits) {
  const float lo = -0.99999994039535522f;  // nextafter(-1,0) in f32
  float f = __uint_as_float((bits >> 9) | 0x3f800000u) - 1.0f;
  float u = fmaxf(lo, f * 2.0f + lo);
  return 1.41421356237309515f * erfinv_xla(u);
}

// ---------------------------------------------------------------------------
// k_pre: S[j] = sum_{t>j} W1 row-block t. One block per j, coalesced float4.
__global__ __launch_bounds__(256) void k_pre(const float* __restrict__ W1,
                                             float* __restrict__ ws) {
  const int j = blockIdx.x;      // 128 blocks
  const int tid = threadIdx.x;
  float4 a0 = {0.f, 0.f, 0.f, 0.f}, a1 = {0.f, 0.f, 0.f, 0.f};
  for (int t = j + 1; t < 128; ++t) {
    const float4* p = (const float4*)(W1 + t * 2048);
    const float4 x0 = p[tid], x1 = p[tid + 256];
    a0.x += x0.x; a0.y += x0.y; a0.z += x0.z; a0.w += x0.w;
    a1.x += x1.x; a1.y += x1.y; a1.z += x1.z; a1.w += x1.w;
  }
  float4* Sj = (float4*)(ws + OFF_S + j * 2048);
  Sj[tid] = a0; Sj[tid + 256] = a1;
  if (j == 127) {  // zero-iteration block zeroes ALL sync state
    for (int i = tid; i < ZERO_CNT; i += 256) ws[OFF_SYNC + i] = 0.0f;
  }
}

// ---------------------------------------------------------------------------
// k_main: cooperative (co-residency only — no grid.sync). 256 blocks x 256.
// Block bk owns 16 samples sharing t = bk>>1: s = t + 128*m, m in
// [(bk&1)*16, +16). Step sync: 8 cells (cell = bk&7, 32 arrivals each) on
// 128B-padded lines; arrival = atomicAdd(partial) + release fetch_add(ctr)
// on ONE private line; wait = lanes 0..7 poll the 8 cells IN PARALLEL, then
// width-8 shfl reduce. (R5's false-shared shards + 16-deep serial poll fixed.)
__global__ void __launch_bounds__(256, 1) k_main(
    const float* __restrict__ emb, const float* __restrict__ W1,
    const float* __restrict__ b1, const float* __restrict__ W2,
    const float* __restrict__ b2, float* __restrict__ out,
    float* __restrict__ ws, KeyArr keys) {
  __shared__ float W1_l[64][32];    // rows t*64 .. t*64+63 of W1
  __shared__ float W2_l[32][64];
  __shared__ float base_l[16][32];
  __shared__ float u_l[16][64];
  __shared__ float score_l[16][64];
  __shared__ float h_l[16][32];
  __shared__ float b2_l[64];
  __shared__ float tW1_l[32];       // W1 last row (time feature)
  __shared__ float wsum[4];
  __shared__ float snorm_sh;
  __shared__ float loss_sh;

  const int tid  = threadIdx.x;
  const int bk   = blockIdx.x;
  const int gtid = bk * 256 + tid;
  const int t    = bk >> 1;
  const int m0   = (bk & 1) * 16;
  const int cell = bk & 7;

  float* S      = ws + OFF_S;
  float* u_g    = ws + OFF_U;
  float* sync   = ws + OFF_SYNC;
  float* loss_g = ws + OFF_LOSS;

  // ---- Phase A: persistent LDS loads ----
#pragma unroll
  for (int r = 0; r < 8; ++r) {
    const int off = r * 256 + tid;
    ((float*)W1_l)[off] = W1[t * 2048 + off];
    ((float*)W2_l)[off] = W2[off];
  }
#pragma unroll
  for (int r = 0; r < 4; ++r)
    ((float*)u_l)[r * 256 + tid] = 0.0f;
  if (tid < 64) b2_l[tid] = b2[tid];
  if (tid < 32) tW1_l[tid] = W1[262144 + tid];     // W1[8192*32 + h]
  if (tid == 0) loss_sh = 0.0f;

  // ---- Phase B: base_l[sl][h] = b1[h] + sum_d emb[b][j][d] * S[j][d][h] ----
#pragma unroll
  for (int r = 0; r < 2; ++r) {
    const int idx = r * 256 + tid;                 // 512 tasks: (sl, h)
    const int sl = idx >> 5, h = idx & 31;
    const int s = t + 128 * (m0 + sl);
    const int j = (s >> 5), b = (s & 31);
    const float* e  = emb + (b * 128 + j) * 64;
    const float* Sr = S + j * 2048 + h;
    float acc = b1[h];
#pragma unroll
    for (int d = 0; d < 64; ++d)
      acc = fmaf(e[d], Sr[d * 32], acc);
    base_l[sl][h] = acc;
  }
  __syncthreads();

  // ---- main loop: 10 SDE steps, padded-shard scalar sync ----
  for (int k = 0; k < kNS; ++k) {
    const float tval = (float)k * 0.1f;
    // layer 1: pre-activation + relu  (thread = (sl, h); W1_l broadcast)
#pragma unroll
    for (int r = 0; r < 2; ++r) {
      const int idx = r * 256 + tid;
      const int sl = idx >> 5, h = idx & 31;
      float pre = fmaf(tval, tW1_l[h], base_l[sl][h]);
#pragma unroll
      for (int d = 0; d < 64; ++d)
        pre = fmaf(u_l[sl][d], W1_l[d][h], pre);
      h_l[sl][h] = fmaxf(pre, 0.0f);
    }
    __syncthreads();
    // layer 2: score + snorm partial  (thread = (sl, c); c consecutive)
    float sq = 0.0f;
#pragma unroll
    for (int r = 0; r < 4; ++r) {
      const int idx = r * 256 + tid;
      const int sl = idx >> 6, c = idx & 63;
      float v = b2_l[c];
#pragma unroll
      for (int hh = 0; hh < 32; ++hh)
        v = fmaf(h_l[sl][hh], W2_l[hh][c], v);
      score_l[sl][c] = v;
      sq = fmaf(v, v, sq);
    }
#pragma unroll
    for (int o = 32; o > 0; o >>= 1) sq += __shfl_down(sq, o);
    if ((tid & 63) == 0) wsum[tid >> 6] = sq;
    __syncthreads();
    // arrive: 2 RMWs on my cell's private 128B line
    if (tid == 0) {
      float* slot = sync + (k * 8 + cell) * 32;
      atomicAdd(slot, wsum[0] + wsum[1] + wsum[2] + wsum[3]);
      __hip_atomic_fetch_add((uint32_t*)(slot + 1), 1u,
                             __ATOMIC_RELEASE, __HIP_MEMORY_SCOPE_AGENT);
    }
    // overlap: threefry noise (snorm-independent) while other blocks arrive
    float nn[4];
    const int d = tid & 63;
#pragma unroll
    for (int r = 0; r < 4; ++r) {
      const int sl = (tid >> 6) * 4 + r;
      const int s = t + 128 * (m0 + sl);
      nn[r] = bits_to_normal(rand_bits(keys.k0[k], keys.k1[k],
                                       (uint32_t)(s * 64 + d))) * 0.31622776601683794f;
    }
    // wait: lanes 0..7 poll the 8 cells in parallel, then width-8 reduce
    float p = 0.0f;
    if (tid < 8) {
      float* slot = sync + (k * 8 + tid) * 32;
      while (__hip_atomic_load((uint32_t*)(slot + 1), __ATOMIC_ACQUIRE,
                               __HIP_MEMORY_SCOPE_AGENT) < 32u)
        __builtin_amdgcn_s_sleep(1);
      p = __hip_atomic_load(slot, __ATOMIC_RELAXED, __HIP_MEMORY_SCOPE_AGENT);
    }
#pragma unroll
    for (int o = 4; o > 0; o >>= 1) p += __shfl_down(p, o, 8);
    if (tid == 0) snorm_sh = sqrtf(p);
    __syncthreads();
    const float snorm = snorm_sh;
    // update u (d-major: consecutive lanes -> conflict-free) + diagonal loss
#pragma unroll
    for (int r = 0; r < 4; ++r) {
      const int sl = (tid >> 6) * 4 + r;           // wave-uniform
      const int s = t + 128 * (m0 + sl);
      const float dx = score_l[sl][d] * 0.05f + snorm * nn[r];
      const float un = u_l[sl][d] + dx;
      u_l[sl][d] = un;
      if ((s & 127) == (s >> 5)) {                 // diagonal sample
        float lq = un * un;
#pragma unroll
        for (int o = 32; o > 0; o >>= 1) lq += __shfl_down(lq, o);
        if ((tid & 63) == 0) atomicAdd(&loss_sh, lq * (1.0f / 64.0f));
      }
    }
    __syncthreads();
  }

  // ---- publish u (agent-scope atomic stores) + padded-shard barrier (k=10) ----
  {
    const int d = tid & 63;
#pragma unroll
    for (int r = 0; r < 4; ++r) {
      const int sl = (tid >> 6) * 4 + r;
      const int s = t + 128 * (m0 + sl);
      __hip_atomic_store(&u_g[s * 64 + d], u_l[sl][d],
                         __ATOMIC_RELAXED, __HIP_MEMORY_SCOPE_AGENT);
    }
  }
  __syncthreads();
  if (tid == 0) {
    atomicAdd(loss_g + 0, loss_sh);
    float* slot = sync + (10 * 8 + cell) * 32;
    __hip_atomic_fetch_add((uint32_t*)(slot + 1), 1u,
                           __ATOMIC_RELEASE, __HIP_MEMORY_SCOPE_AGENT);
  }
  if (tid < 8) {
    float* slot = sync + (10 * 8 + tid) * 32;
    while (__hip_atomic_load((uint32_t*)(slot + 1), __ATOMIC_ACQUIRE,
                             __HIP_MEMORY_SCOPE_AGENT) < 32u)
      __builtin_amdgcn_s_sleep(1);
  }
  __syncthreads();

  // ---- final: assemble xt output (verified R1 index map) + |emb-xt| ----
  float lab = 0.0f;
#pragma unroll
  for (int r = 0; r < 4; ++r) {
    const int g = r * 65536 + gtid;                // covers 262144
    const int dd = g & 63, bi = g >> 6, i = bi & 127, b = bi >> 7;
    const int mm = i * 32 + b, bp = mm >> 7, tt = mm & 127;
    const int s2 = i * 32 + bp;
    float v = 0.0f;
    if (i < tt) v = emb[(bp * 128 + i) * 64 + dd];
    if ((s2 & 127) == tt)
      v += __hip_atomic_load(&u_g[s2 * 64 + dd], __ATOMIC_RELAXED, __HIP_MEMORY_SCOPE_AGENT);
    out[g] = v;
    lab += fabsf(emb[g] - v);
  }
#pragma unroll
  for (int o = 32; o > 0; o >>= 1) lab += __shfl_down(lab, o);
  if ((tid & 63) == 0) wsum[tid >> 6] = lab;
  __syncthreads();
  if (tid == 0) {
    atomicAdd(loss_g + 1, wsum[0] + wsum[1] + wsum[2] + wsum[3]);
    const uint32_t old = __hip_atomic_fetch_add((uint32_t*)loss_g + 2, 1u,
                         __ATOMIC_ACQ_REL, __HIP_MEMORY_SCOPE_AGENT);
    if (old == 255u) {  // last block: all loss adds visible
      out[262144] = __hip_atomic_load(loss_g + 0, __ATOMIC_RELAXED, __HIP_MEMORY_SCOPE_AGENT);
      out[262145] = __hip_atomic_load(loss_g + 1, __ATOMIC_RELAXED, __HIP_MEMORY_SCOPE_AGENT)
                    * (1.0f / 262144.0f);
    }
  }
}

// ---------------------------------------------------------------------------
static void compute_step_keys(KeyArr& ka) {
  for (int i = 0; i < kNS; ++i) {
    uint32_t y0, y1;
    tf2x32(0u, 42u, 0u, (uint32_t)i, y0, y1);
    ka.k0[i] = y0; ka.k1[i] = y1;
  }
}

extern "C" void kernel_launch(void* const* d_in, const int* in_sizes, int n_in,
                              void* d_out, int out_size, void* d_ws, size_t ws_size,
                              hipStream_t stream) {
  (void)in_sizes; (void)n_in; (void)out_size; (void)ws_size;
  const float* emb = (const float*)d_in[0];
  const float* W1  = (const float*)d_in[1];
  const float* b1  = (const float*)d_in[2];
  const float* W2  = (const float*)d_in[3];
  const float* b2  = (const float*)d_in[4];
  float* out = (float*)d_out;
  float* ws  = (float*)d_ws;

  KeyArr ka;
  compute_step_keys(ka);

  k_pre<<<128, 256, 0, stream>>>(W1, ws);

  void* args[] = {(void*)&emb, (void*)&W1, (void*)&b1, (void*)&W2, (void*)&b2,
                  (void*)&out, (void*)&ws, (void*)&ka};
  hipLaunchCooperativeKernel((const void*)k_main, dim3(256), dim3(256),
                             args, 0, stream);
}